// Round 3
// baseline (153.537 us; speedup 1.0000x reference)
//
#include <hip/hip_runtime.h>

// Problem constants (from reference)
constexpr int BATCH = 1024;
constexpr int H     = 128;
constexpr int Wd    = 128;
constexpr int WPAD  = 132;   // padded width (pad 2 each side)
constexpr int KH    = 10;
constexpr int KW    = 10;
constexpr int STR   = 5;
constexpr int NKH   = 25;
constexpr int NKW   = 25;
constexpr int NK    = NKH * NKW;   // 625
constexpr int KSZ   = KH * KW;     // 100

constexpr int IMGS  = 5;                       // images per iteration
constexpr int ITERS = 3;                       // iterations per block
constexpr int IPB   = IMGS * ITERS;            // 15
constexpr int NGRP  = (BATCH + IPB - 1) / IPB; // 69 (last group partial)
constexpr int XST   = 136;  // staged row stride (floats): [4 zeros][128 data][4 slack]
constexpr int WG2_STRIDE = 52;                 // 50 weights + 2 pad (16B-aligned rows)
constexpr int WG2_ROWS   = NKH * 5 * KH;       // 1250 (ki, kjgrp, di)
constexpr int WG2_FLOATS = WG2_ROWS * WG2_STRIDE; // 65000

// Re-gather dense W into per-(ki,kjgrp,di) contiguous rows of 50 weights:
// wg2[(ki*5+g)*10+di][kl*10+dj] = kernel_weights[ki*25+5g+kl][di][dj]
__global__ void gather_w(const float* __restrict__ W, float* __restrict__ wg2) {
    int t = blockIdx.x * blockDim.x + threadIdx.x;
    if (t >= WG2_ROWS * 50) return;
    int grp = t / 50, e = t % 50;
    int kl = e / 10, dj = e % 10;
    int di = grp % 10, gg = (grp / 10) % 5, ki = grp / 50;
    int kj = 5 * gg + kl;
    int k  = ki * NKW + kj;
    int row = (ki * STR + di) * WPAD + (kj * STR + dj);
    wg2[grp * WG2_STRIDE + e] = W[row * NK + k];
}

// 50 FMAs with compile-time alignment offset O into the f[36] register file.
template <int O>
__device__ __forceinline__ void dot50(const float* __restrict__ f,
                                      const float* __restrict__ w,
                                      float* __restrict__ s) {
#pragma unroll
    for (int kl = 0; kl < 5; ++kl) {
        float a = 0.f;
#pragma unroll
        for (int dj = 0; dj < 10; ++dj)
            a += f[O + 5 * kl + dj] * w[kl * 10 + dj];
        s[kl] = a;
    }
}

// Block = (ki, 15-image group). Thread (img, di, kjgrp): 50 weights in regs,
// 9 x ds_read_b128 per image, 50 FMAs, 5 partials; 125 threads reduce+store.
template <bool USE_WG>
__global__ __launch_bounds__(256, 4)
void lc2d_kernel(const float* __restrict__ x,
                 const float* __restrict__ wg2,
                 const float* __restrict__ Wfull,
                 const float* __restrict__ bias,
                 float* __restrict__ out) {
    __shared__ float xs[IMGS][KH][XST];      // 27.2 KB
    __shared__ float part[IMGS][NKW][12];    // 6 KB

    const int bid = blockIdx.x;
    const int ki  = bid % NKH;               // ki-fastest: neighbors share images
    const int grp = bid / NKH;
    const int tid = threadIdx.x;

    const bool active = tid < IMGS * KH * 5; // 250
    const int img = tid / 50;                // 0..4
    const int di  = (tid / 5) % 10;          // 0..9 (also the staged row)
    const int g   = tid % 5;                 // kj group 5g..5g+4

    const int r0 = ki * STR - 2;
    const int rg = r0 + di;                  // global row this thread stages
    const bool rowok = (rg >= 0);            // rg <= 127 always

    // ---- one-time: 50 weights into registers ----
    float w[50];
    if (active) {
        if (USE_WG) {
            const float4* src = reinterpret_cast<const float4*>(
                wg2 + (size_t)(((ki * 5 + g) * 10 + di) * WG2_STRIDE));
            float tmp[52];
#pragma unroll
            for (int q = 0; q < 13; ++q) {
                float4 v = src[q];
                tmp[4 * q] = v.x; tmp[4 * q + 1] = v.y;
                tmp[4 * q + 2] = v.z; tmp[4 * q + 3] = v.w;
            }
#pragma unroll
            for (int i = 0; i < 50; ++i) w[i] = tmp[i];
        } else {
#pragma unroll
            for (int kl = 0; kl < 5; ++kl) {
                const int kj = 5 * g + kl, kcol = ki * NKW + kj;
#pragma unroll
                for (int dj = 0; dj < 10; ++dj) {
                    int row = (ki * STR + di) * WPAD + kj * STR + dj;
                    w[kl * 10 + dj] = Wfull[row * NK + kcol];
                }
            }
        }
    }

    // ---- one-time: bias + reduce-role indices ----
    float bval = 0.f;
    int himg = 0, hkj = 0;
    if (tid < IMGS * NKW) {                  // 125
        himg = tid / NKW; hkj = tid % NKW;
        bval = bias[ki * NKW + hkj];
    }

    const int sb = (25 * g + 2) & ~3;        // aligned LDS read base (floats)
    const int o  = (25 * g + 2) & 3;         // in-register offset

    // ---- staging: thread writes quads q = g*7+jj of row (img, di) ----
    auto stage = [&](int it) {
        if (!active) return;
        const int b = grp * IPB + it * IMGS + img;
        const bool bok = (b < BATCH) && rowok;
        const float* xr = x + ((size_t)b << 14) + ((size_t)rg << 7);
        float* dst = &xs[img][di][0];
#pragma unroll
        for (int jj = 0; jj < 7; ++jj) {
            const int q = g * 7 + jj;        // 33 quads per row (q0 = zeros)
            if (q < 33) {
                float4 v = make_float4(0.f, 0.f, 0.f, 0.f);
                if (q > 0 && bok)
                    v = *reinterpret_cast<const float4*>(xr + 4 * q - 4);
                *reinterpret_cast<float4*>(dst + 4 * q) = v;
            }
        }
    };

    stage(0);
    __syncthreads();

    for (int it = 0;; ++it) {
        // ---- compute: 9 b128 LDS reads -> 50 FMAs -> 5 partials ----
        if (active) {
            float f[36];
            const float* src = &xs[img][di][sb];
#pragma unroll
            for (int q = 0; q < 9; ++q) {
                float4 v = *reinterpret_cast<const float4*>(src + 4 * q);
                f[4 * q] = v.x; f[4 * q + 1] = v.y;
                f[4 * q + 2] = v.z; f[4 * q + 3] = v.w;
            }
            float s[5];
            switch (o) {
                case 0: dot50<0>(f, w, s); break;
                case 1: dot50<1>(f, w, s); break;
                case 2: dot50<2>(f, w, s); break;
                default: dot50<3>(f, w, s); break;
            }
#pragma unroll
            for (int kl = 0; kl < 5; ++kl)
                part[img][5 * g + kl][di] = s[kl];
        }
        __syncthreads();

        // ---- reduce over di + bias + store (125 threads) ----
        if (tid < IMGS * NKW) {
            const int b = grp * IPB + it * IMGS + himg;
            if (b < BATCH) {
                const float* p = &part[himg][hkj][0];
                float4 a = *reinterpret_cast<const float4*>(p);
                float4 c = *reinterpret_cast<const float4*>(p + 4);
                float2 e = *reinterpret_cast<const float2*>(p + 8);
                float ssum = ((a.x + a.y) + (a.z + a.w))
                           + ((c.x + c.y) + (c.z + c.w)) + (e.x + e.y);
                out[(size_t)b * NK + ki * NKW + hkj] = ssum + bval;
            }
        }
        if (it + 1 == ITERS) break;
        stage(it + 1);          // overlaps reduce (different LDS arrays)
        __syncthreads();
    }
}

extern "C" void kernel_launch(void* const* d_in, const int* in_sizes, int n_in,
                              void* d_out, int out_size, void* d_ws, size_t ws_size,
                              hipStream_t stream) {
    const float* x    = (const float*)d_in[0];
    const float* W    = (const float*)d_in[1];
    const float* bias = (const float*)d_in[2];
    float* out = (float*)d_out;

    const dim3 grid(NKH * NGRP);
    if (ws_size >= (size_t)WG2_FLOATS * sizeof(float)) {
        float* wg2 = (float*)d_ws;
        gather_w<<<(WG2_ROWS * 50 + 255) / 256, 256, 0, stream>>>(W, wg2);
        lc2d_kernel<true><<<grid, 256, 0, stream>>>(x, wg2, W, bias, out);
    } else {
        lc2d_kernel<false><<<grid, 256, 0, stream>>>(x, nullptr, W, bias, out);
    }
}

// Round 5
// 139.974 us; speedup vs baseline: 1.0969x; 1.0969x over previous
//
#include <hip/hip_runtime.h>

typedef _Float16 f16x2 __attribute__((ext_vector_type(2)));
typedef __fp16  fp16x2 __attribute__((ext_vector_type(2)));

// Problem constants
constexpr int NKH  = 25, NKW = 25, NK = 625;
constexpr int WPAD = 132;                    // reference padded width
constexpr int IMGS = 10;                     // images per block
constexpr int NGRP = (1024 + IMGS - 1) / IMGS;  // 103
constexpr int ROW_U2 = 34;                   // uint2 per staged row (136 halves)
constexpr int IMG_U2 = 342;                  // uint2 stride per image (8-half pad)
constexpr int WPT  = 160;                    // padded halves per (ki,kj)

union U2H { unsigned int u; f16x2 h; fp16x2 p; };

// ---- gather: dense W -> f16 weights zero-padded to 16-slot rows at offset o ----
// wgp[k][di][p] = (p-o in [0,10)) ? W[((ki*5+di)*132 + kj*5 + (p-o)) * 625 + k] : 0
// where o = (5*kj+2) & 3 matches the aligned LDS window h0 = (5*kj+2) & ~3.
__global__ void gather_wp(const float* __restrict__ W, _Float16* __restrict__ wgp) {
    int t = blockIdx.x * 256 + threadIdx.x;
    if (t >= NK * WPT) return;
    int k = t / WPT, rem = t % WPT;
    int di = rem >> 4, p = rem & 15;
    int ki = k / NKW, kj = k % NKW;
    int o = (5 * kj + 2) & 3;
    int j = p - o;
    float val = 0.f;
    if (j >= 0 && j < 10)
        val = W[(size_t)((ki * 5 + di) * WPAD + kj * 5 + j) * NK + k];
    wgp[t] = (_Float16)val;
}

__device__ __forceinline__ float dot2acc(unsigned int a, unsigned int b, float c) {
    U2H ua, ub; ua.u = a; ub.u = b;
#if __has_builtin(__builtin_amdgcn_fdot2)
    return __builtin_amdgcn_fdot2(ua.h, ub.h, c, false);
#else
    return c + (float)ua.h.x * (float)ub.h.x + (float)ua.h.y * (float)ub.h.y;
#endif
}

// Block = (ki, 10-image group). Thread = (img, kj). x staged as f16 in LDS
// (left-pad 4, row 136 halves). Uniform per-lane code: 4 ds_read_b64 + 8 fdot2
// per di row; alignment folded into zero-padded weights (NO divergent switch).
template <bool USE_WG>
__global__ __launch_bounds__(256, 4)
void lc2d_f16(const float* __restrict__ x, const _Float16* __restrict__ wgp,
              const float* __restrict__ Wfull,
              const float* __restrict__ bias, float* __restrict__ out) {
    __shared__ uint2 xs2[IMGS * IMG_U2];   // 27360 B

    const int bid = blockIdx.x;
    const int ki  = bid % NKH;             // ki-fastest: adjacent blocks share x rows
    const int grp = bid / NKH;
    const int tid = threadIdx.x;

    // ---- staging: 10 img x 10 rows x 34 uint2 (q0/q33 zeros; q1..32 = float4->4 f16)
    const int r0 = ki * 5 - 2;
    for (int i = tid; i < IMGS * 340; i += 256) {
        const int im = i / 340, rem = i % 340;
        const int r = rem / 34, q = rem % 34;
        const int rg = r0 + r;
        const int b  = grp * IMGS + im;
        uint2 val = make_uint2(0u, 0u);
        if (q >= 1 && q <= 32 && rg >= 0 && b < 1024) {
            const float4 v = *reinterpret_cast<const float4*>(
                x + ((size_t)b << 14) + (rg << 7) + ((q - 1) << 2));  // 16B-aligned
            U2H u0, u1;
            u0.p = __builtin_amdgcn_cvt_pkrtz(v.x, v.y);
            u1.p = __builtin_amdgcn_cvt_pkrtz(v.z, v.w);
            val.x = u0.u; val.y = u1.u;
        }
        xs2[im * IMG_U2 + r * ROW_U2 + q] = val;
    }

    // ---- weights: 80 half2 (160 padded halves) into VGPRs, once per block ----
    const bool active = tid < IMGS * NKW;   // 250
    const int img = tid / NKW, kj = tid % NKW;
    const int k = ki * NKW + kj;
    unsigned int wv[80];
    float bval = 0.f;
    if (active) {
        if (USE_WG) {
            const uint4* wp = reinterpret_cast<const uint4*>(wgp + (size_t)k * WPT);
#pragma unroll
            for (int t4 = 0; t4 < 20; ++t4) {
                uint4 u = wp[t4];
                wv[4 * t4 + 0] = u.x; wv[4 * t4 + 1] = u.y;
                wv[4 * t4 + 2] = u.z; wv[4 * t4 + 3] = u.w;
            }
        } else {
            const int o = (5 * kj + 2) & 3;
#pragma unroll
            for (int di = 0; di < 10; ++di) {
#pragma unroll
                for (int m = 0; m < 8; ++m) {
                    float f0 = 0.f, f1 = 0.f;
                    int j0 = 2 * m - o, j1 = 2 * m + 1 - o;
                    if (j0 >= 0 && j0 < 10)
                        f0 = Wfull[(size_t)((ki * 5 + di) * WPAD + kj * 5 + j0) * NK + k];
                    if (j1 >= 0 && j1 < 10)
                        f1 = Wfull[(size_t)((ki * 5 + di) * WPAD + kj * 5 + j1) * NK + k];
                    U2H u; u.p = __builtin_amdgcn_cvt_pkrtz(f0, f1);
                    wv[di * 8 + m] = u.u;
                }
            }
        }
        bval = bias[k];
    }
    __syncthreads();

    if (!active) return;

    // aligned 16-half window [h0, h0+15]; real data at h0+o .. h0+o+9
    const int h0 = (5 * kj + 2) & ~3;
    const uint2* base = xs2 + img * IMG_U2 + (h0 >> 2);
    float acc = 0.f;
#pragma unroll
    for (int di = 0; di < 10; ++di) {
        const uint2 a0 = base[di * ROW_U2 + 0];
        const uint2 a1 = base[di * ROW_U2 + 1];
        const uint2 a2 = base[di * ROW_U2 + 2];
        const uint2 a3 = base[di * ROW_U2 + 3];
        const unsigned int* w8 = &wv[di * 8];
        acc = dot2acc(a0.x, w8[0], acc);
        acc = dot2acc(a0.y, w8[1], acc);
        acc = dot2acc(a1.x, w8[2], acc);
        acc = dot2acc(a1.y, w8[3], acc);
        acc = dot2acc(a2.x, w8[4], acc);
        acc = dot2acc(a2.y, w8[5], acc);
        acc = dot2acc(a3.x, w8[6], acc);
        acc = dot2acc(a3.y, w8[7], acc);
    }
    const int b = grp * IMGS + img;
    if (b < 1024)
        out[(size_t)b * NK + k] = acc + bval;
}

extern "C" void kernel_launch(void* const* d_in, const int* in_sizes, int n_in,
                              void* d_out, int out_size, void* d_ws, size_t ws_size,
                              hipStream_t stream) {
    const float* x    = (const float*)d_in[0];
    const float* W    = (const float*)d_in[1];
    const float* bias = (const float*)d_in[2];
    float* out = (float*)d_out;

    const dim3 grid(NKH * NGRP);   // 2575
    if (ws_size >= (size_t)NK * WPT * sizeof(_Float16)) {
        _Float16* wgp = (_Float16*)d_ws;
        gather_wp<<<(NK * WPT + 255) / 256, 256, 0, stream>>>(W, wgp);
        lc2d_f16<true><<<grid, 256, 0, stream>>>(x, wgp, W, bias, out);
    } else {
        lc2d_f16<false><<<grid, 256, 0, stream>>>(x, nullptr, W, bias, out);
    }
}

// Round 6
// 135.387 us; speedup vs baseline: 1.1341x; 1.0339x over previous
//
#include <hip/hip_runtime.h>

typedef _Float16 f16x2 __attribute__((ext_vector_type(2)));
typedef __fp16  fp16x2 __attribute__((ext_vector_type(2)));

// Problem constants
constexpr int NKW  = 25, NK = 625;
constexpr int WPADR = 132;                  // reference padded width
constexpr int WPT   = 160;                  // padded halves per (ki,kj) weight row

union U2H { unsigned int u; f16x2 h; fp16x2 p; };

// ---- gather: dense W -> f16 weights zero-padded to 16-slot rows at offset o ----
// wgp[k][di*16+p] = (p-o in [0,10)) ? W[((ki*5+di)*132 + kj*5 + (p-o)) * 625 + k] : 0
// where o = (5*kj+2) & 3 matches the aligned window h0 = (5*kj+2) & ~3.
__global__ void gather_wp(const float* __restrict__ W, _Float16* __restrict__ wgp) {
    int t = blockIdx.x * 256 + threadIdx.x;
    if (t >= NK * WPT) return;
    int k = t / WPT, rem = t % WPT;
    int di = rem >> 4, p = rem & 15;
    int ki = k / NKW, kj = k % NKW;
    int o = (5 * kj + 2) & 3;
    int j = p - o;
    float val = 0.f;
    if (j >= 0 && j < 10)
        val = W[(size_t)((ki * 5 + di) * WPADR + kj * 5 + j) * NK + k];
    wgp[t] = (_Float16)val;
}

__device__ __forceinline__ float dot2acc(unsigned int a, unsigned int b, float c) {
    U2H ua, ub; ua.u = a; ub.u = b;
#if __has_builtin(__builtin_amdgcn_fdot2)
    return __builtin_amdgcn_fdot2(ua.h, ub.h, c, false);
#else
    return c + (float)ua.h.x * (float)ub.h.x + (float)ua.h.y * (float)ub.h.y;
#endif
}

// Block = (image b, half). Stage the half-image as f16 rows (stride 34 uint2 =
// 136 halves: [2 pad][128 data][2 pad][4 slack]); compute all 300/325 outputs
// of the half. Alignment folded into zero-padded weights: every lane runs the
// identical 4x ds_read_b64 + 8x fdot2 per di row. Weights read per-output from
// global (200KB working set, L2-resident), in 2 chunks of 10 uint4 to cap VGPRs.
template <bool USE_WG>
__global__ __launch_bounds__(256, 4)
void lc2d_img(const float* __restrict__ x, const _Float16* __restrict__ wgp,
              const float* __restrict__ Wfull,
              const float* __restrict__ bias, float* __restrict__ out) {
    __shared__ uint2 xs[70 * 34];           // 19040 B (half0 uses 70 rows, half1 65)

    const int b    = blockIdx.x;
    const int half = blockIdx.y;
    const int P0   = half ? 65 : 0;         // first staged padded row
    const int NR   = half ? 65 : 70;        // staged rows
    const int K0   = half ? 13 : 0;         // first ki of this half
    const int NOUT = half ? 300 : 325;      // outputs (NKI*25)
    const int tid  = threadIdx.x;

    // zero boundary uint2 (q=0 -> padded cols 0..3, q=33 -> cols 132..135 slack)
    for (int i = tid; i < NR * 2; i += 256)
        xs[(i >> 1) * 34 + (i & 1) * 33] = make_uint2(0u, 0u);

    // stage: NR rows x 32 quads, pure shift/mask indexing, float4 coalesced
    const float* xb = x + ((size_t)b << 14);
    for (int i = tid; i < NR * 32; i += 256) {
        const int idx = i >> 5, q = (i & 31) + 1;
        const int r = P0 + idx - 2;         // unpadded row
        uint2 val = make_uint2(0u, 0u);
        if (r >= 0 && r < 128) {
            const float4 v = *reinterpret_cast<const float4*>(xb + (r << 7) + ((q - 1) << 2));
            U2H u0, u1;
            u0.p = __builtin_amdgcn_cvt_pkrtz(v.x, v.y);
            u1.p = __builtin_amdgcn_cvt_pkrtz(v.z, v.w);
            val.x = u0.u; val.y = u1.u;
        }
        xs[idx * 34 + q] = val;
    }
    __syncthreads();

    const uint4* wgp16 = reinterpret_cast<const uint4*>(wgp);

    for (int k_local = tid; k_local < NOUT; k_local += 256) {
        const int k    = K0 * 25 + k_local;
        const int ki_l = k_local / 25;                  // const-div -> mul/shift
        const int kj   = k_local - ki_l * 25;
        const uint2* base = xs + ki_l * 5 * 34 + ((5 * kj + 2) >> 2);
        float acc = bias[k];
#pragma unroll
        for (int c = 0; c < 2; ++c) {
            uint4 wq[10];                                // 40 VGPRs live
            if (USE_WG) {
#pragma unroll
                for (int j = 0; j < 10; ++j) wq[j] = wgp16[k * 20 + c * 10 + j];
            } else {
                const int o = (5 * kj + 2) & 3;
#pragma unroll
                for (int j = 0; j < 10; ++j) {
                    const int di = c * 5 + (j >> 1);
                    const int pb = (j & 1) * 8;
                    unsigned int uu[4];
#pragma unroll
                    for (int m = 0; m < 4; ++m) {
                        float f0 = 0.f, f1 = 0.f;
                        const int j0 = pb + 2 * m - o, j1 = pb + 2 * m + 1 - o;
                        const size_t rowb = (size_t)(((K0 + ki_l) * 5 + di) * WPADR + kj * 5);
                        if (j0 >= 0 && j0 < 10) f0 = Wfull[(rowb + j0) * NK + k];
                        if (j1 >= 0 && j1 < 10) f1 = Wfull[(rowb + j1) * NK + k];
                        U2H u; u.p = __builtin_amdgcn_cvt_pkrtz(f0, f1);
                        uu[m] = u.u;
                    }
                    wq[j] = make_uint4(uu[0], uu[1], uu[2], uu[3]);
                }
            }
#pragma unroll
            for (int d2 = 0; d2 < 5; ++d2) {
                const uint2* rowp = base + (c * 5 + d2) * 34;
                const uint2 a0 = rowp[0], a1 = rowp[1], a2 = rowp[2], a3 = rowp[3];
                const uint4 wA = wq[d2 * 2], wB = wq[d2 * 2 + 1];
                acc = dot2acc(a0.x, wA.x, acc);
                acc = dot2acc(a0.y, wA.y, acc);
                acc = dot2acc(a1.x, wA.z, acc);
                acc = dot2acc(a1.y, wA.w, acc);
                acc = dot2acc(a2.x, wB.x, acc);
                acc = dot2acc(a2.y, wB.y, acc);
                acc = dot2acc(a3.x, wB.z, acc);
                acc = dot2acc(a3.y, wB.w, acc);
            }
        }
        out[(size_t)b * NK + k] = acc;
    }
}

extern "C" void kernel_launch(void* const* d_in, const int* in_sizes, int n_in,
                              void* d_out, int out_size, void* d_ws, size_t ws_size,
                              hipStream_t stream) {
    const float* x    = (const float*)d_in[0];
    const float* W    = (const float*)d_in[1];
    const float* bias = (const float*)d_in[2];
    float* out = (float*)d_out;

    const dim3 grid(1024, 2);
    if (ws_size >= (size_t)NK * WPT * sizeof(_Float16)) {
        _Float16* wgp = (_Float16*)d_ws;
        gather_wp<<<(NK * WPT + 255) / 256, 256, 0, stream>>>(W, wgp);
        lc2d_img<true><<<grid, 256, 0, stream>>>(x, wgp, W, bias, out);
    } else {
        lc2d_img<false><<<grid, 256, 0, stream>>>(x, nullptr, W, bias, out);
    }
}

// Round 7
// 127.849 us; speedup vs baseline: 1.2009x; 1.0590x over previous
//
#include <hip/hip_runtime.h>

typedef _Float16 f16x2 __attribute__((ext_vector_type(2)));
typedef __fp16  fp16x2 __attribute__((ext_vector_type(2)));

// Problem constants
constexpr int NKW  = 25, NK = 625;
constexpr int WPADR = 132;                  // reference padded width
constexpr int WPT   = 160;                  // padded halves per (ki,kj) weight row
constexpr int RST   = 35;                   // LDS row stride in uint2 (was 34; +1 anti-conflict)

union U2H { unsigned int u; f16x2 h; fp16x2 p; };

// ---- gather: dense W -> f16 weights, zero-padded 16-slot rows, TRANSPOSED ----
// Layout: wgpT as uint4[20][625]; slot j of output k holds padded halves 8j..8j+7.
// Padded row (per k): di = p>>4, in-row slot p&15, real data at slot o..o+9 where
// o = (5*kj+2) & 3, matching the aligned LDS window h0 = (5*kj+2) & ~3.
__global__ void gather_wp(const float* __restrict__ W, _Float16* __restrict__ wgpT) {
    int t = blockIdx.x * 256 + threadIdx.x;
    if (t >= NK * WPT) return;
    int k = t / WPT, p = t % WPT;
    int di = p >> 4, s = p & 15;
    int ki = k / NKW, kj = k % NKW;
    int o = (5 * kj + 2) & 3;
    int j = s - o;
    float val = 0.f;
    if (j >= 0 && j < 10)
        val = W[(size_t)((ki * 5 + di) * WPADR + kj * 5 + j) * NK + k];
    wgpT[((size_t)(p >> 3) * NK + k) * 8 + (p & 7)] = (_Float16)val;
}

__device__ __forceinline__ float dot2acc(unsigned int a, unsigned int b, float c) {
    U2H ua, ub; ua.u = a; ub.u = b;
#if __has_builtin(__builtin_amdgcn_fdot2)
    return __builtin_amdgcn_fdot2(ua.h, ub.h, c, false);
#else
    return c + (float)ua.h.x * (float)ub.h.x + (float)ua.h.y * (float)ub.h.y;
#endif
}

// Block = (image b, half). Stage the half-image as f16 rows ([2 pad][128 data]
// [2 pad][slack], stride 35 uint2); compute all 325/300 outputs of the half.
// Alignment folded into zero-padded weights: uniform 4x ds_read_b64 + 8x fdot2
// per di row, no divergence. Weights: 20 uint4, lane-coalesced (transposed
// layout), loaded as ONE batch -> 20 L2 loads in flight (fixes R6's VGPR=32
// register starvation that serialized them).
template <bool USE_WG>
__global__ __launch_bounds__(256, 2)
void lc2d_img(const float* __restrict__ x, const _Float16* __restrict__ wgpT,
              const float* __restrict__ Wfull,
              const float* __restrict__ bias, float* __restrict__ out) {
    __shared__ uint2 xs[70 * RST];          // 19600 B

    const int b    = blockIdx.x;
    const int half = blockIdx.y;
    const int P0   = half ? 65 : 0;         // first staged padded row
    const int NR   = half ? 65 : 70;        // staged rows
    const int K0   = half ? 13 : 0;         // first ki of this half
    const int NOUT = half ? 300 : 325;      // outputs
    const int tid  = threadIdx.x;

    // zero boundary uint2 (q=0 -> halves 0..3 incl. left pad; q=33 -> right pad+slack)
    for (int i = tid; i < NR * 2; i += 256)
        xs[(i >> 1) * RST + (i & 1) * 33] = make_uint2(0u, 0u);

    // stage: NR rows x 32 quads, shift/mask indexing, float4 coalesced
    const float* xb = x + ((size_t)b << 14);
    for (int i = tid; i < NR * 32; i += 256) {
        const int idx = i >> 5, q = (i & 31) + 1;
        const int r = P0 + idx - 2;         // unpadded row
        uint2 val = make_uint2(0u, 0u);
        if (r >= 0 && r < 128) {
            const float4 v = *reinterpret_cast<const float4*>(xb + (r << 7) + ((q - 1) << 2));
            U2H u0, u1;
            u0.p = __builtin_amdgcn_cvt_pkrtz(v.x, v.y);
            u1.p = __builtin_amdgcn_cvt_pkrtz(v.z, v.w);
            val.x = u0.u; val.y = u1.u;
        }
        xs[idx * RST + q] = val;
    }
    __syncthreads();

    const uint4* wt4 = reinterpret_cast<const uint4*>(wgpT);

    for (int k_local = tid; k_local < NOUT; k_local += 256) {
        const int k    = K0 * NKW + k_local;
        const int ki_l = k_local / 25;
        const int kj   = k_local - ki_l * 25;
        const uint2* base = xs + ki_l * 5 * RST + ((5 * kj + 2) >> 2);

        // ---- all 20 weight uint4 in one batch: coalesced, 20 loads in flight
        uint4 wq[20];
        if (USE_WG) {
#pragma unroll
            for (int j = 0; j < 20; ++j) wq[j] = wt4[(size_t)j * NK + k];
        } else {
            const int o = (5 * kj + 2) & 3;
#pragma unroll
            for (int j = 0; j < 20; ++j) {
                const int di = j >> 1, pb = (j & 1) * 8;
                unsigned int uu[4];
#pragma unroll
                for (int m = 0; m < 4; ++m) {
                    float f0 = 0.f, f1 = 0.f;
                    const int j0 = pb + 2 * m - o, j1 = pb + 2 * m + 1 - o;
                    const size_t rowb = (size_t)(((K0 + ki_l) * 5 + di) * WPADR + kj * 5);
                    if (j0 >= 0 && j0 < 10) f0 = Wfull[(rowb + j0) * NK + k];
                    if (j1 >= 0 && j1 < 10) f1 = Wfull[(rowb + j1) * NK + k];
                    U2H u; u.p = __builtin_amdgcn_cvt_pkrtz(f0, f1);
                    uu[m] = u.u;
                }
                wq[j] = make_uint4(uu[0], uu[1], uu[2], uu[3]);
            }
        }

        float acc0 = bias[k], acc1 = 0.f;   // dual accumulators: halve dep chain
#pragma unroll
        for (int d = 0; d < 10; ++d) {
            const uint2* rowp = base + d * RST;
            const uint2 a0 = rowp[0], a1 = rowp[1], a2 = rowp[2], a3 = rowp[3];
            const uint4 wA = wq[2 * d], wB = wq[2 * d + 1];
            acc0 = dot2acc(a0.x, wA.x, acc0);
            acc1 = dot2acc(a0.y, wA.y, acc1);
            acc0 = dot2acc(a1.x, wA.z, acc0);
            acc1 = dot2acc(a1.y, wA.w, acc1);
            acc0 = dot2acc(a2.x, wB.x, acc0);
            acc1 = dot2acc(a2.y, wB.y, acc1);
            acc0 = dot2acc(a3.x, wB.z, acc0);
            acc1 = dot2acc(a3.y, wB.w, acc1);
        }
        out[(size_t)b * NK + k] = acc0 + acc1;
    }
}

extern "C" void kernel_launch(void* const* d_in, const int* in_sizes, int n_in,
                              void* d_out, int out_size, void* d_ws, size_t ws_size,
                              hipStream_t stream) {
    const float* x    = (const float*)d_in[0];
    const float* W    = (const float*)d_in[1];
    const float* bias = (const float*)d_in[2];
    float* out = (float*)d_out;

    const dim3 grid(1024, 2);
    if (ws_size >= (size_t)NK * WPT * sizeof(_Float16)) {
        _Float16* wgpT = (_Float16*)d_ws;
        gather_wp<<<(NK * WPT + 255) / 256, 256, 0, stream>>>(W, wgpT);
        lc2d_img<true><<<grid, 256, 0, stream>>>(x, wgpT, W, bias, out);
    } else {
        lc2d_img<false><<<grid, 256, 0, stream>>>(x, nullptr, W, bias, out);
    }
}